// Round 12
// baseline (1430.203 us; speedup 1.0000x reference)
//
#include <hip/hip_runtime.h>
#include <math.h>

#define BB 64
#define T_SUB 512
#define WW 256
#define DD 768
#define HH 20
#define CAP_DIM 10
#define IN_DIM 778
#define KPAD 800
#define G4 80     // 4*H
#define NOUT 160

#define NPROD 512   // producer blocks (64 b x 8 groups of 32 words)
#define NLSTM 128   // consumer blocks (2 dir x 64 b)

typedef _Float16 f16x8 __attribute__((ext_vector_type(8)));
typedef float f32x4 __attribute__((ext_vector_type(4)));

// ws layout (bytes):
//   wpad  : [160][800] f16  @ 0        (256,000 B)
//   seg   : int2[16384]     @ 256,000  (131,072 B)
//   flags : int[512]        @ 387,072  (2,048 B)    -- zeroed each call
//   gpre  : [16384][160] f32@ 389,120  (10,485,760 B) -- cols PERMUTED, bias folded
#define WP_OFF   ((size_t)0)
#define SEG_OFF  ((size_t)256000)
#define FL_OFF   ((size_t)387072)
#define GP_OFF   ((size_t)389120)

// ---------------- K0: pad weights (blocks 0..159) + segment search (160..223)
__global__ __launch_bounds__(256) void k_prep(
    const float* __restrict__ wf, const float* __restrict__ wb,
    const int* __restrict__ b2t,
    _Float16* __restrict__ wp, int2* __restrict__ seg)
{
    int blk = blockIdx.x;
    if (blk < NOUT) {
        int j = blk;
        const float* src = (j < G4) ? (wf + (size_t)j * IN_DIM)
                                    : (wb + (size_t)(j - G4) * IN_DIM);
        for (int k = threadIdx.x; k < KPAD; k += 256)
            wp[(size_t)j * KPAD + k] = (k < IN_DIM) ? (_Float16)src[k] : (_Float16)0.f;
    } else {
        int b = blk - NOUT, w = threadIdx.x;
        const int* row = b2t + (size_t)b * T_SUB;
        int lo = 0, hi = T_SUB;
        while (lo < hi) { int m = (lo + hi) >> 1; if (row[m] < w) lo = m + 1; else hi = m; }
        int lo2 = lo, hi2 = T_SUB;
        while (lo2 < hi2) { int m = (lo2 + hi2) >> 1; if (row[m] < w + 1) lo2 = m + 1; else hi2 = m; }
        seg[(size_t)b * WW + w] = make_int2(lo, lo2 - lo);
    }
}

__device__ __forceinline__ void waitg(const int* flags, int idx) {
    long iters = 0;
    while (__hip_atomic_load(&flags[idx], __ATOMIC_ACQUIRE,
                             __HIP_MEMORY_SCOPE_AGENT) == 0) {
        __builtin_amdgcn_s_sleep(2);
        if (++iters > 200000000L) break;   // hang failsafe
    }
}

// ---------------- K1: persistent mega-kernel --------------------------------
// blocks 0..511   : producer (b = blk&63, group G = GORD[blk>>6]) — mean of
//                   32 words -> LDS f16 tile -> MFMA gemm (bias folded, cols
//                   permuted) -> gpre -> release flag[b*8+G].
// blocks 512..639 : R10-proven LSTM chain (dir = r>>6, b = r&63); staging
//                   waves acquire-spin on the chunk's two group flags.
__global__ __launch_bounds__(256) void k_mega(
    const float* __restrict__ hiddens, const int2* __restrict__ seg,
    const int* __restrict__ cap_inds, const float* __restrict__ cap_table,
    const _Float16* __restrict__ wp,
    const float* __restrict__ bias_f, const float* __restrict__ bias_b,
    const float* __restrict__ whh_f, const float* __restrict__ whh_b,
    float* __restrict__ gpre, int* __restrict__ flags,
    float* __restrict__ out)
{
    __shared__ __align__(16) char smem[51712];   // max(prod 51712, lstm 40960)
    int blk = blockIdx.x;
    int t = threadIdx.x;

    if (blk < NPROD) {
        // ================= producer =================
        const int GORD[8] = {0, 7, 1, 6, 2, 5, 3, 4};
        int gidx = blk >> 6;
        int b    = blk & 63;
        int G    = GORD[gidx];
        int w0   = G * 32;
        _Float16 (*xt)[808] = (_Float16(*)[808])smem;

        // ---- mean phase: 32 rows x 100 d8-items ----
        for (int i = t; i < 3200; i += 256) {
            int row = i / 100, d8 = i % 100;
            int bw = b * WW + w0 + row;
            f16x8 r;
            if (d8 < 96) {
                int2 sg = seg[bw];
                int lo = sg.x, cnt = sg.y;
                const size_t LSTR = (size_t)BB * (T_SUB + 1) * DD;
                const float* base = hiddens + ((size_t)b * (T_SUB + 1) + lo + 1) * DD + d8 * 8;
                float a[8];
#pragma unroll
                for (int q = 0; q < 8; q++) a[q] = 0.f;
                if (cnt == 2) {
#pragma unroll
                    for (int l = 0; l < 3; ++l) {
                        float4 v0 = *(const float4*)(base + l * LSTR);
                        float4 v1 = *(const float4*)(base + l * LSTR + 4);
                        float4 v2 = *(const float4*)(base + l * LSTR + DD);
                        float4 v3 = *(const float4*)(base + l * LSTR + DD + 4);
                        a[0] += v0.x + v2.x; a[1] += v0.y + v2.y;
                        a[2] += v0.z + v2.z; a[3] += v0.w + v2.w;
                        a[4] += v1.x + v3.x; a[5] += v1.y + v3.y;
                        a[6] += v1.z + v3.z; a[7] += v1.w + v3.w;
                    }
                } else {
                    for (int l = 0; l < 3; ++l)
                        for (int ti = 0; ti < cnt; ++ti) {
                            const float* p = base + l * LSTR + (size_t)ti * DD;
                            float4 v0 = *(const float4*)(p);
                            float4 v1 = *(const float4*)(p + 4);
                            a[0] += v0.x; a[1] += v0.y; a[2] += v0.z; a[3] += v0.w;
                            a[4] += v1.x; a[5] += v1.y; a[6] += v1.z; a[7] += v1.w;
                        }
                }
                float inv = 1.0f / (3.0f * (float)(cnt > 0 ? cnt : 1));
#pragma unroll
                for (int q = 0; q < 8; q++) r[q] = (_Float16)(a[q] * inv);
            } else {
                int ci = cap_inds[bw];
#pragma unroll
                for (int q = 0; q < 8; q++) {
                    int c = (d8 - 96) * 8 + q;
                    r[q] = (c < CAP_DIM) ? (_Float16)cap_table[ci * CAP_DIM + c] : (_Float16)0.f;
                }
            }
            *(f16x8*)(&xt[row][d8 * 8]) = r;
        }
        __syncthreads();

        // ---- gemm phase: waves 0,1 (16 rows each), N=160, K=800 ----
        int wv = t >> 6, lane = t & 63;
        if (wv < 2) {
            int lrow = wv * 16 + (lane & 15);
            int koff = (lane >> 4) * 8;
            const _Float16* bp = wp + (size_t)(lane & 15) * KPAD + koff;
            f32x4 acc[10];
#pragma unroll
            for (int i = 0; i < 10; i++)
#pragma unroll
                for (int r = 0; r < 4; r++) acc[i][r] = 0.f;
            for (int k0 = 0; k0 < KPAD; k0 += 32) {
                f16x8 af = *(const f16x8*)(&xt[lrow][k0 + koff]);
#pragma unroll
                for (int nf = 0; nf < 10; nf++) {
                    f16x8 bf = *(const f16x8*)(bp + (size_t)nf * 16 * KPAD + k0);
                    acc[nf] = __builtin_amdgcn_mfma_f32_16x16x32_f16(af, bf, acc[nf], 0, 0, 0);
                }
            }
            // C/D: col=lane&15, row=(lane>>4)*4+reg [m89]. Permute + bias fold.
            int orow = b * WW + w0 + wv * 16 + (lane >> 4) * 4;
            int ocol = lane & 15;
#pragma unroll
            for (int nf = 0; nf < 10; nf++) {
                int col = nf * 16 + ocol;
                int dir = (col >= G4) ? 1 : 0;
                int g = col - dir * G4;
                int pcol = dir * G4 + (g % 40) * 2 + (g / 40);
                float bv = (dir ? bias_b : bias_f)[g];
#pragma unroll
                for (int r = 0; r < 4; r++)
                    gpre[(size_t)(orow + r) * NOUT + pcol] = acc[nf][r] + bv;
            }
        }
        __syncthreads();
        __threadfence();
        if (t == 0)
            __hip_atomic_store(&flags[b * 8 + G], 1, __ATOMIC_RELEASE,
                               __HIP_MEMORY_SCOPE_AGENT);
    } else {
        // ================= LSTM consumer (R10-proven body + flag waits) =====
        int r_ = blk - NPROD;
        int dir  = r_ >> 6;
        int b    = r_ & 63;
        int wv   = t >> 6;
        int lane = t & 63;
        float (*gbuf)[64 * G4] = (float(*)[64 * G4])smem;   // [2][5120]
        const float* gsrc = gpre + (size_t)b * WW * NOUT + dir * G4;

        // initial stage: chunk 0 (wait its two 32-word groups first)
        {
            int base = dir ? 192 : 0;
            int g0 = base >> 5;
            waitg(flags, b * 8 + g0);
            waitg(flags, b * 8 + g0 + 1);
            __threadfence();
            for (int f = t; f < 1280; f += 256) {
                int row = f / 20, q = f % 20;
                float4 v = *(const float4*)(gsrc + (size_t)(base + row) * NOUT + q * 4);
                *(float4*)(&gbuf[0][row * G4 + q * 4]) = v;
            }
        }

        const float* whh = dir ? whh_b : whh_f;
        int j = lane & 31; if (j > 19) j = 19;
        bool low = lane < 32;
        float mm = low ? 1.f : 2.f;
        float aa = low ? 0.f : -1.f;
        int coff = low ? (40 + 2 * j) : (2 * j);
        float w0r[HH], w1r[HH];
        if (wv == 0) {
            int r0 = low ? (20 + j) : j;
            int r1 = low ? (60 + j) : (40 + j);
#pragma unroll
            for (int k = 0; k < HH; k++) {
                w0r[k] = whh[r0 * HH + k];
                w1r[k] = whh[r1 * HH + k];
            }
        }
        __syncthreads();

        float h = 0.f, c = 0.f;
        int w = dir ? (WW - 1) : 0;
        int stepd = dir ? -1 : 1;

        for (int ch = 0; ch < 4; ++ch) {
            int cb = ch & 1;
            if (wv > 0) {
                if (ch + 1 < 4) {
                    int nbase = dir ? (192 - (ch + 1) * 64) : (ch + 1) * 64;
                    int g0 = nbase >> 5;
                    waitg(flags, b * 8 + g0);
                    waitg(flags, b * 8 + g0 + 1);
                    __threadfence();
                    for (int f = t - 64; f < 1280; f += 192) {
                        int row = f / 20, q = f % 20;
                        float4 v = *(const float4*)(gsrc + (size_t)(nbase + row) * NOUT + q * 4);
                        *(float4*)(&gbuf[cb ^ 1][row * G4 + q * 4]) = v;
                    }
                }
            } else {
                int base = dir ? (192 - ch * 64) : ch * 64;
                float2 pre = *(const float2*)(&gbuf[cb][(w - base) * G4 + coff]);
                for (int sl = 0; sl < 64; ++sl) {
                    int wn = w + stepd;
                    float2 nxt = make_float2(0.f, 0.f);
                    if (sl < 63)
                        nxt = *(const float2*)(&gbuf[cb][(wn - base) * G4 + coff]);
                    float a0a = pre.x, a0b = 0.f, a1a = pre.y, a1b = 0.f;
#pragma unroll
                    for (int k = 0; k < 10; k++) {
                        float hk  = __uint_as_float(__builtin_amdgcn_readlane(__float_as_uint(h), k));
                        float hk2 = __uint_as_float(__builtin_amdgcn_readlane(__float_as_uint(h), k + 10));
                        a0a = fmaf(hk,  w0r[k],      a0a);
                        a1a = fmaf(hk,  w1r[k],      a1a);
                        a0b = fmaf(hk2, w0r[k + 10], a0b);
                        a1b = fmaf(hk2, w1r[k + 10], a1b);
                    }
                    float a0 = a0a + a0b, a1 = a1a + a1b;
                    float u0 = 1.f / (1.f + __expf(-a0));          // sig(f) | sig(i)
                    float uu = 1.f / (1.f + __expf(-mm * a1));
                    float u1 = fmaf(uu, mm, aa);                   // sig(o) | tanh(g)
                    float p  = u0 * u1;
                    {   // partner value via permlane32_swap (XOR-robust, R10-proven)
                        unsigned int a_ = __float_as_uint(p);
                        typedef unsigned int uint2v __attribute__((ext_vector_type(2)));
                        uint2v rr = __builtin_amdgcn_permlane32_swap(a_, a_, false, false);
                        p = __uint_as_float(rr[0] ^ rr[1] ^ a_);
                    }
                    c = fmaf(u0, c, p);
                    float tc = fmaf(2.f, 1.f / (1.f + __expf(-2.f * c)), -1.f);
                    h = u1 * tc;
                    if (lane < HH)
                        out[((size_t)b * WW + w) * (2 * HH) + dir * HH + lane] = h;
                    pre = nxt;
                    w = wn;
                }
            }
            __syncthreads();
        }
    }
}

extern "C" void kernel_launch(void* const* d_in, const int* in_sizes, int n_in,
                              void* d_out, int out_size, void* d_ws, size_t ws_size,
                              hipStream_t stream) {
    const float* hiddens   = (const float*)d_in[0];
    const int*   bert2toks = (const int*)d_in[1];
    const int*   cap_inds  = (const int*)d_in[2];
    const float* cap_table = (const float*)d_in[3];
    const float* w_ih_f    = (const float*)d_in[4];
    const float* w_hh_f    = (const float*)d_in[5];
    const float* b_f       = (const float*)d_in[6];
    const float* w_ih_b    = (const float*)d_in[7];
    const float* w_hh_b    = (const float*)d_in[8];
    const float* b_b       = (const float*)d_in[9];
    float* out = (float*)d_out;

    _Float16* wpad  = (_Float16*)((char*)d_ws + WP_OFF);
    int2*     seg   = (int2*)((char*)d_ws + SEG_OFF);
    int*      flags = (int*)((char*)d_ws + FL_OFF);
    float*    gpre  = (float*)((char*)d_ws + GP_OFF);

    hipMemsetAsync(flags, 0, NPROD / 64 * 64 * sizeof(int), stream);  // 512 ints
    k_prep<<<NOUT + BB, 256, 0, stream>>>(w_ih_f, w_ih_b, bert2toks, wpad, seg);
    k_mega<<<NPROD + NLSTM, 256, 0, stream>>>(hiddens, seg, cap_inds, cap_table,
                                              wpad, b_f, b_b, w_hh_f, w_hh_b,
                                              gpre, flags, out);
}

// Round 13
// 275.486 us; speedup vs baseline: 5.1916x; 5.1916x over previous
//
#include <hip/hip_runtime.h>
#include <math.h>

#define BB 64
#define T_SUB 512
#define WW 256
#define DD 768
#define HH 20
#define CAP_DIM 10
#define IN_DIM 778
#define KPAD 800
#define G4 80     // 4*H
#define NOUT 160

#define NPROD 512   // producer blocks (64 b x 8 groups of 32 words)
#define NLSTM 128   // consumer blocks (2 dir x 64 b)

typedef _Float16 f16x8 __attribute__((ext_vector_type(8)));
typedef float f32x4 __attribute__((ext_vector_type(4)));

// ws layout (bytes):
//   wpad  : [160][800] f16  @ 0        (256,000 B)
//   seg   : int2[16384]     @ 256,000  (131,072 B)
//   flags : int[512]        @ 387,072  (2,048 B)    -- zeroed each call
//   gpre  : [16384][160] f32@ 389,120  (10,485,760 B) -- cols PERMUTED, bias folded
#define WP_OFF   ((size_t)0)
#define SEG_OFF  ((size_t)256000)
#define FL_OFF   ((size_t)387072)
#define GP_OFF   ((size_t)389120)

// ---------------- K0: pad weights (blocks 0..159) + segment search (160..223)
__global__ __launch_bounds__(256) void k_prep(
    const float* __restrict__ wf, const float* __restrict__ wb,
    const int* __restrict__ b2t,
    _Float16* __restrict__ wp, int2* __restrict__ seg)
{
    int blk = blockIdx.x;
    if (blk < NOUT) {
        int j = blk;
        const float* src = (j < G4) ? (wf + (size_t)j * IN_DIM)
                                    : (wb + (size_t)(j - G4) * IN_DIM);
        for (int k = threadIdx.x; k < KPAD; k += 256)
            wp[(size_t)j * KPAD + k] = (k < IN_DIM) ? (_Float16)src[k] : (_Float16)0.f;
    } else {
        int b = blk - NOUT, w = threadIdx.x;
        const int* row = b2t + (size_t)b * T_SUB;
        int lo = 0, hi = T_SUB;
        while (lo < hi) { int m = (lo + hi) >> 1; if (row[m] < w) lo = m + 1; else hi = m; }
        int lo2 = lo, hi2 = T_SUB;
        while (lo2 < hi2) { int m = (lo2 + hi2) >> 1; if (row[m] < w + 1) lo2 = m + 1; else hi2 = m; }
        seg[(size_t)b * WW + w] = make_int2(lo, lo2 - lo);
    }
}

// RELAXED spin (no L1 invalidate per poll!) — R12's ACQUIRE-per-poll emitted a
// buffer_wbinvl1_vol each iteration and collapsed producer BW 50x.
__device__ __forceinline__ void waitg_relaxed(const int* flags, int idx) {
    long iters = 0;
    while (__hip_atomic_load(&flags[idx], __ATOMIC_RELAXED,
                             __HIP_MEMORY_SCOPE_AGENT) == 0) {
        __builtin_amdgcn_s_sleep(8);
        if (++iters > 20000000L) break;   // hang failsafe
    }
}

// ---------------- K1: persistent mega-kernel --------------------------------
__global__ __launch_bounds__(256) void k_mega(
    const float* __restrict__ hiddens, const int2* __restrict__ seg,
    const int* __restrict__ cap_inds, const float* __restrict__ cap_table,
    const _Float16* __restrict__ wp,
    const float* __restrict__ bias_f, const float* __restrict__ bias_b,
    const float* __restrict__ whh_f, const float* __restrict__ whh_b,
    float* __restrict__ gpre, int* __restrict__ flags,
    float* __restrict__ out)
{
    __shared__ __align__(16) char smem[51712];   // max(prod 51712, lstm 40960)
    int blk = blockIdx.x;
    int t = threadIdx.x;

    if (blk < NPROD) {
        // ================= producer =================
        const int GORD[8] = {0, 7, 1, 6, 2, 5, 3, 4};
        int gidx = blk >> 6;
        int b    = blk & 63;
        int G    = GORD[gidx];
        int w0   = G * 32;
        _Float16 (*xt)[808] = (_Float16(*)[808])smem;

        // ---- mean phase: 32 rows x 100 d8-items ----
        for (int i = t; i < 3200; i += 256) {
            int row = i / 100, d8 = i % 100;
            int bw = b * WW + w0 + row;
            f16x8 r;
            if (d8 < 96) {
                int2 sg = seg[bw];
                int lo = sg.x, cnt = sg.y;
                const size_t LSTR = (size_t)BB * (T_SUB + 1) * DD;
                const float* base = hiddens + ((size_t)b * (T_SUB + 1) + lo + 1) * DD + d8 * 8;
                float a[8];
#pragma unroll
                for (int q = 0; q < 8; q++) a[q] = 0.f;
                if (cnt == 2) {
#pragma unroll
                    for (int l = 0; l < 3; ++l) {
                        float4 v0 = *(const float4*)(base + l * LSTR);
                        float4 v1 = *(const float4*)(base + l * LSTR + 4);
                        float4 v2 = *(const float4*)(base + l * LSTR + DD);
                        float4 v3 = *(const float4*)(base + l * LSTR + DD + 4);
                        a[0] += v0.x + v2.x; a[1] += v0.y + v2.y;
                        a[2] += v0.z + v2.z; a[3] += v0.w + v2.w;
                        a[4] += v1.x + v3.x; a[5] += v1.y + v3.y;
                        a[6] += v1.z + v3.z; a[7] += v1.w + v3.w;
                    }
                } else {
                    for (int l = 0; l < 3; ++l)
                        for (int ti = 0; ti < cnt; ++ti) {
                            const float* p = base + l * LSTR + (size_t)ti * DD;
                            float4 v0 = *(const float4*)(p);
                            float4 v1 = *(const float4*)(p + 4);
                            a[0] += v0.x; a[1] += v0.y; a[2] += v0.z; a[3] += v0.w;
                            a[4] += v1.x; a[5] += v1.y; a[6] += v1.z; a[7] += v1.w;
                        }
                }
                float inv = 1.0f / (3.0f * (float)(cnt > 0 ? cnt : 1));
#pragma unroll
                for (int q = 0; q < 8; q++) r[q] = (_Float16)(a[q] * inv);
            } else {
                int ci = cap_inds[bw];
#pragma unroll
                for (int q = 0; q < 8; q++) {
                    int c = (d8 - 96) * 8 + q;
                    r[q] = (c < CAP_DIM) ? (_Float16)cap_table[ci * CAP_DIM + c] : (_Float16)0.f;
                }
            }
            *(f16x8*)(&xt[row][d8 * 8]) = r;
        }
        __syncthreads();

        // ---- gemm phase: waves 0,1 (16 rows each), N=160, K=800 ----
        int wv = t >> 6, lane = t & 63;
        if (wv < 2) {
            int lrow = wv * 16 + (lane & 15);
            int koff = (lane >> 4) * 8;
            const _Float16* bp = wp + (size_t)(lane & 15) * KPAD + koff;
            f32x4 acc[10];
#pragma unroll
            for (int i = 0; i < 10; i++)
#pragma unroll
                for (int r = 0; r < 4; r++) acc[i][r] = 0.f;
            for (int k0 = 0; k0 < KPAD; k0 += 32) {
                f16x8 af = *(const f16x8*)(&xt[lrow][k0 + koff]);
#pragma unroll
                for (int nf = 0; nf < 10; nf++) {
                    f16x8 bf = *(const f16x8*)(bp + (size_t)nf * 16 * KPAD + k0);
                    acc[nf] = __builtin_amdgcn_mfma_f32_16x16x32_f16(af, bf, acc[nf], 0, 0, 0);
                }
            }
            // C/D: col=lane&15, row=(lane>>4)*4+reg [m89]. Permute + bias fold.
            int orow = b * WW + w0 + wv * 16 + (lane >> 4) * 4;
            int ocol = lane & 15;
#pragma unroll
            for (int nf = 0; nf < 10; nf++) {
                int col = nf * 16 + ocol;
                int dir = (col >= G4) ? 1 : 0;
                int g = col - dir * G4;
                int pcol = dir * G4 + (g % 40) * 2 + (g / 40);
                float bv = (dir ? bias_b : bias_f)[g];
#pragma unroll
                for (int r = 0; r < 4; r++)
                    gpre[(size_t)(orow + r) * NOUT + pcol] = acc[nf][r] + bv;
            }
        }
        __syncthreads();
        __threadfence();
        if (t == 0)
            __hip_atomic_store(&flags[b * 8 + G], 1, __ATOMIC_RELEASE,
                               __HIP_MEMORY_SCOPE_AGENT);
    } else {
        // ================= LSTM consumer (R10-proven body + relaxed waits) ==
        int r_ = blk - NPROD;
        int dir  = r_ >> 6;
        int b    = r_ & 63;
        int wv   = t >> 6;
        int lane = t & 63;
        float (*gbuf)[64 * G4] = (float(*)[64 * G4])smem;   // [2][5120]
        const float* gsrc = gpre + (size_t)b * WW * NOUT + dir * G4;

        // initial stage: chunk 0 (wait its two 32-word groups first)
        {
            int base = dir ? 192 : 0;
            int g0 = base >> 5;
            waitg_relaxed(flags, b * 8 + g0);
            waitg_relaxed(flags, b * 8 + g0 + 1);
            __builtin_amdgcn_fence(__ATOMIC_ACQUIRE, "agent");  // one L1 inv
            for (int f = t; f < 1280; f += 256) {
                int row = f / 20, q = f % 20;
                float4 v = *(const float4*)(gsrc + (size_t)(base + row) * NOUT + q * 4);
                *(float4*)(&gbuf[0][row * G4 + q * 4]) = v;
            }
        }

        const float* whh = dir ? whh_b : whh_f;
        int j = lane & 31; if (j > 19) j = 19;
        bool low = lane < 32;
        float mm = low ? 1.f : 2.f;
        float aa = low ? 0.f : -1.f;
        int coff = low ? (40 + 2 * j) : (2 * j);
        float w0r[HH], w1r[HH];
        if (wv == 0) {
            int r0 = low ? (20 + j) : j;
            int r1 = low ? (60 + j) : (40 + j);
#pragma unroll
            for (int k = 0; k < HH; k++) {
                w0r[k] = whh[r0 * HH + k];
                w1r[k] = whh[r1 * HH + k];
            }
        }
        __syncthreads();

        float h = 0.f, c = 0.f;
        int w = dir ? (WW - 1) : 0;
        int stepd = dir ? -1 : 1;

        for (int ch = 0; ch < 4; ++ch) {
            int cb = ch & 1;
            if (wv > 0) {
                if (ch + 1 < 4) {
                    int nbase = dir ? (192 - (ch + 1) * 64) : (ch + 1) * 64;
                    int g0 = nbase >> 5;
                    waitg_relaxed(flags, b * 8 + g0);
                    waitg_relaxed(flags, b * 8 + g0 + 1);
                    __builtin_amdgcn_fence(__ATOMIC_ACQUIRE, "agent");
                    for (int f = t - 64; f < 1280; f += 192) {
                        int row = f / 20, q = f % 20;
                        float4 v = *(const float4*)(gsrc + (size_t)(nbase + row) * NOUT + q * 4);
                        *(float4*)(&gbuf[cb ^ 1][row * G4 + q * 4]) = v;
                    }
                }
            } else {
                int base = dir ? (192 - ch * 64) : ch * 64;
                float2 pre = *(const float2*)(&gbuf[cb][(w - base) * G4 + coff]);
                for (int sl = 0; sl < 64; ++sl) {
                    int wn = w + stepd;
                    float2 nxt = make_float2(0.f, 0.f);
                    if (sl < 63)
                        nxt = *(const float2*)(&gbuf[cb][(wn - base) * G4 + coff]);
                    float a0a = pre.x, a0b = 0.f, a1a = pre.y, a1b = 0.f;
#pragma unroll
                    for (int k = 0; k < 10; k++) {
                        float hk  = __uint_as_float(__builtin_amdgcn_readlane(__float_as_uint(h), k));
                        float hk2 = __uint_as_float(__builtin_amdgcn_readlane(__float_as_uint(h), k + 10));
                        a0a = fmaf(hk,  w0r[k],      a0a);
                        a1a = fmaf(hk,  w1r[k],      a1a);
                        a0b = fmaf(hk2, w0r[k + 10], a0b);
                        a1b = fmaf(hk2, w1r[k + 10], a1b);
                    }
                    float a0 = a0a + a0b, a1 = a1a + a1b;
                    float u0 = 1.f / (1.f + __expf(-a0));          // sig(f) | sig(i)
                    float uu = 1.f / (1.f + __expf(-mm * a1));
                    float u1 = fmaf(uu, mm, aa);                   // sig(o) | tanh(g)
                    float p  = u0 * u1;
                    {   // partner value via permlane32_swap (XOR-robust)
                        unsigned int a_ = __float_as_uint(p);
                        typedef unsigned int uint2v __attribute__((ext_vector_type(2)));
                        uint2v rr = __builtin_amdgcn_permlane32_swap(a_, a_, false, false);
                        p = __uint_as_float(rr[0] ^ rr[1] ^ a_);
                    }
                    c = fmaf(u0, c, p);
                    float tc = fmaf(2.f, 1.f / (1.f + __expf(-2.f * c)), -1.f);
                    h = u1 * tc;
                    if (lane < HH)
                        out[((size_t)b * WW + w) * (2 * HH) + dir * HH + lane] = h;
                    pre = nxt;
                    w = wn;
                }
            }
            __syncthreads();
        }
    }
}

extern "C" void kernel_launch(void* const* d_in, const int* in_sizes, int n_in,
                              void* d_out, int out_size, void* d_ws, size_t ws_size,
                              hipStream_t stream) {
    const float* hiddens   = (const float*)d_in[0];
    const int*   bert2toks = (const int*)d_in[1];
    const int*   cap_inds  = (const int*)d_in[2];
    const float* cap_table = (const float*)d_in[3];
    const float* w_ih_f    = (const float*)d_in[4];
    const float* w_hh_f    = (const float*)d_in[5];
    const float* b_f       = (const float*)d_in[6];
    const float* w_ih_b    = (const float*)d_in[7];
    const float* w_hh_b    = (const float*)d_in[8];
    const float* b_b       = (const float*)d_in[9];
    float* out = (float*)d_out;

    _Float16* wpad  = (_Float16*)((char*)d_ws + WP_OFF);
    int2*     seg   = (int2*)((char*)d_ws + SEG_OFF);
    int*      flags = (int*)((char*)d_ws + FL_OFF);
    float*    gpre  = (float*)((char*)d_ws + GP_OFF);

    hipMemsetAsync(flags, 0, 512 * sizeof(int), stream);
    k_prep<<<NOUT + BB, 256, 0, stream>>>(w_ih_f, w_ih_b, bert2toks, wpad, seg);
    k_mega<<<NPROD + NLSTM, 256, 0, stream>>>(hiddens, seg, cap_inds, cap_table,
                                              wpad, b_f, b_b, w_hh_f, w_hh_b,
                                              gpre, flags, out);
}

// Round 14
// 167.535 us; speedup vs baseline: 8.5367x; 1.6443x over previous
//
#include <hip/hip_runtime.h>
#include <math.h>

#define BB 64
#define T_SUB 512
#define WW 256
#define DD 768
#define HH 20
#define CAP_DIM 10
#define IN_DIM 778
#define KPAD 800
#define G4 80     // 4*H
#define NOUT 160

typedef _Float16 f16x8 __attribute__((ext_vector_type(8)));
typedef float f32x4 __attribute__((ext_vector_type(4)));
typedef unsigned int uint2v __attribute__((ext_vector_type(2)));

// ws layout (bytes):
//   wpad : [160][800] f16   @ 0          (256,000 B)
//   seg  : int2[16384]      @ 256,000    (131,072 B)
//   x    : [16384][800] f16 @ 387,072    (26,214,400 B)
#define WP_OFF   ((size_t)0)
#define SEG_OFF  ((size_t)256000)
#define X_OFF    ((size_t)387072)

#define NMEAN 3200   // mean blocks (2 d8-items per thread)
#define NPREP 224    // 160 weight-pad blocks + 64 segment-search blocks

// ---------------- K1: mean (blocks 0..3199) + prep (blocks 3200..3423) ------
// Mean: thread handles items (bw,d2) and (bw,d2+50) — SAME row → one seg read,
// 24 global loads issued before any accumulate (2x MLP vs R11's k_mean).
__global__ __launch_bounds__(256) void k_mean_prep(
    const float* __restrict__ hiddens, const int* __restrict__ b2t,
    const int* __restrict__ cap_inds, const float* __restrict__ cap_table,
    const float* __restrict__ wf, const float* __restrict__ wb,
    _Float16* __restrict__ x, _Float16* __restrict__ wp, int2* __restrict__ seg)
{
    int blk = blockIdx.x;
    if (blk >= NMEAN) {
        int pb = blk - NMEAN;
        if (pb < NOUT) {
            const float* src = (pb < G4) ? (wf + (size_t)pb * IN_DIM)
                                         : (wb + (size_t)(pb - G4) * IN_DIM);
            for (int k = threadIdx.x; k < KPAD; k += 256)
                wp[(size_t)pb * KPAD + k] = (k < IN_DIM) ? (_Float16)src[k] : (_Float16)0.f;
        } else {
            int b = pb - NOUT, w = threadIdx.x;
            const int* row = b2t + (size_t)b * T_SUB;
            int lo = 0, hi = T_SUB;
            while (lo < hi) { int m = (lo + hi) >> 1; if (row[m] < w) lo = m + 1; else hi = m; }
            int lo2 = lo, hi2 = T_SUB;
            while (lo2 < hi2) { int m = (lo2 + hi2) >> 1; if (row[m] < w + 1) lo2 = m + 1; else hi2 = m; }
            seg[(size_t)b * WW + w] = make_int2(lo, lo2 - lo);
        }
        return;
    }

    int idx = blk * 256 + threadIdx.x;      // 16384*50
    int d2 = idx % 50;                      // item A: d8=d2 (<50, always mean)
    int bw = idx / 50;                      // item B: d8=d2+50 (mean if <96)
    int b = bw >> 8;

    // segment bounds via on-the-fly binary search? No — seg not ready; compute
    // directly from b2t (independent of prep blocks).
    int lo, cnt;
    {
        int w = bw & 255;
        const int* row = b2t + (size_t)b * T_SUB;
        int l0 = 0, hi = T_SUB;
        while (l0 < hi) { int m = (l0 + hi) >> 1; if (row[m] < w) l0 = m + 1; else hi = m; }
        int l2 = l0, hi2 = T_SUB;
        while (l2 < hi2) { int m = (l2 + hi2) >> 1; if (row[m] < w + 1) l2 = m + 1; else hi2 = m; }
        lo = l0; cnt = l2 - l0;
    }
    const size_t LSTR = (size_t)BB * (T_SUB + 1) * DD;
    const float* rowp = hiddens + ((size_t)b * (T_SUB + 1) + lo + 1) * DD;
    float inv = 1.0f / (3.0f * (float)(cnt > 0 ? cnt : 1));
    bool bmean = (d2 + 50) < 96;            // item B is a mean item (d2<46)
    f16x8 ra, rb;

    if (cnt == 2 && bmean) {
        // fast path: all 24 loads issued up-front, then accumulate
        const float* pa = rowp + d2 * 8;
        const float* pb_ = rowp + (d2 + 50) * 8;
        float4 A0, A1, A2, A3, A4, A5, A6, A7, A8, A9, Aa, Ab;
        float4 B0, B1, B2, B3, B4, B5, B6, B7, B8, B9, Ba, Bb;
        A0 = *(const float4*)(pa);                A1 = *(const float4*)(pa + 4);
        A2 = *(const float4*)(pa + DD);           A3 = *(const float4*)(pa + DD + 4);
        A4 = *(const float4*)(pa + LSTR);         A5 = *(const float4*)(pa + LSTR + 4);
        A6 = *(const float4*)(pa + LSTR + DD);    A7 = *(const float4*)(pa + LSTR + DD + 4);
        A8 = *(const float4*)(pa + 2*LSTR);       A9 = *(const float4*)(pa + 2*LSTR + 4);
        Aa = *(const float4*)(pa + 2*LSTR + DD);  Ab = *(const float4*)(pa + 2*LSTR + DD + 4);
        B0 = *(const float4*)(pb_);               B1 = *(const float4*)(pb_ + 4);
        B2 = *(const float4*)(pb_ + DD);          B3 = *(const float4*)(pb_ + DD + 4);
        B4 = *(const float4*)(pb_ + LSTR);        B5 = *(const float4*)(pb_ + LSTR + 4);
        B6 = *(const float4*)(pb_ + LSTR + DD);   B7 = *(const float4*)(pb_ + LSTR + DD + 4);
        B8 = *(const float4*)(pb_ + 2*LSTR);      B9 = *(const float4*)(pb_ + 2*LSTR + 4);
        Ba = *(const float4*)(pb_ + 2*LSTR + DD); Bb = *(const float4*)(pb_ + 2*LSTR + DD + 4);
        ra[0] = (_Float16)((A0.x+A2.x+A4.x+A6.x+A8.x+Aa.x) * inv);
        ra[1] = (_Float16)((A0.y+A2.y+A4.y+A6.y+A8.y+Aa.y) * inv);
        ra[2] = (_Float16)((A0.z+A2.z+A4.z+A6.z+A8.z+Aa.z) * inv);
        ra[3] = (_Float16)((A0.w+A2.w+A4.w+A6.w+A8.w+Aa.w) * inv);
        ra[4] = (_Float16)((A1.x+A3.x+A5.x+A7.x+A9.x+Ab.x) * inv);
        ra[5] = (_Float16)((A1.y+A3.y+A5.y+A7.y+A9.y+Ab.y) * inv);
        ra[6] = (_Float16)((A1.z+A3.z+A5.z+A7.z+A9.z+Ab.z) * inv);
        ra[7] = (_Float16)((A1.w+A3.w+A5.w+A7.w+A9.w+Ab.w) * inv);
        rb[0] = (_Float16)((B0.x+B2.x+B4.x+B6.x+B8.x+Ba.x) * inv);
        rb[1] = (_Float16)((B0.y+B2.y+B4.y+B6.y+B8.y+Ba.y) * inv);
        rb[2] = (_Float16)((B0.z+B2.z+B4.z+B6.z+B8.z+Ba.z) * inv);
        rb[3] = (_Float16)((B0.w+B2.w+B4.w+B6.w+B8.w+Ba.w) * inv);
        rb[4] = (_Float16)((B1.x+B3.x+B5.x+B7.x+B9.x+Bb.x) * inv);
        rb[5] = (_Float16)((B1.y+B3.y+B5.y+B7.y+B9.y+Bb.y) * inv);
        rb[6] = (_Float16)((B1.z+B3.z+B5.z+B7.z+B9.z+Bb.z) * inv);
        rb[7] = (_Float16)((B1.w+B3.w+B5.w+B7.w+B9.w+Bb.w) * inv);
    } else {
        // general path (any cnt; item B may be caps)
        float a[8], bacc[8];
#pragma unroll
        for (int q = 0; q < 8; q++) { a[q] = 0.f; bacc[q] = 0.f; }
        for (int l = 0; l < 3; ++l)
            for (int ti = 0; ti < cnt; ++ti) {
                const float* p = rowp + l * LSTR + (size_t)ti * DD;
                float4 v0 = *(const float4*)(p + d2 * 8);
                float4 v1 = *(const float4*)(p + d2 * 8 + 4);
                a[0]+=v0.x; a[1]+=v0.y; a[2]+=v0.z; a[3]+=v0.w;
                a[4]+=v1.x; a[5]+=v1.y; a[6]+=v1.z; a[7]+=v1.w;
                if (bmean) {
                    float4 u0 = *(const float4*)(p + (d2 + 50) * 8);
                    float4 u1 = *(const float4*)(p + (d2 + 50) * 8 + 4);
                    bacc[0]+=u0.x; bacc[1]+=u0.y; bacc[2]+=u0.z; bacc[3]+=u0.w;
                    bacc[4]+=u1.x; bacc[5]+=u1.y; bacc[6]+=u1.z; bacc[7]+=u1.w;
                }
            }
#pragma unroll
        for (int q = 0; q < 8; q++) { ra[q] = (_Float16)(a[q] * inv); rb[q] = (_Float16)(bacc[q] * inv); }
    }
    if (!bmean) {   // item B is caps/pad (d8b in 96..99)
        int ci = cap_inds[bw];
#pragma unroll
        for (int q = 0; q < 8; q++) {
            int c = (d2 + 50 - 96) * 8 + q;
            rb[q] = (c < CAP_DIM) ? (_Float16)cap_table[ci * CAP_DIM + c] : (_Float16)0.f;
        }
    }
    *(f16x8*)(x + (size_t)bw * KPAD + d2 * 8) = ra;
    *(f16x8*)(x + (size_t)bw * KPAD + (d2 + 50) * 8) = rb;
}

// ---------------- K2: FUSED gemm+LSTM (R11-proven) + setprio ----------------
__device__ __forceinline__ float xchg32(float v) {
    unsigned int a = __float_as_uint(v);
    uint2v r = __builtin_amdgcn_permlane32_swap(a, a, false, false);
    return __uint_as_float(r[0] ^ r[1] ^ a);   // partner lane's value (lane ^ 32)
}

__global__ __launch_bounds__(320) void k_lstm(
    const _Float16* __restrict__ x, const _Float16* __restrict__ wp,
    const float* __restrict__ bias_f, const float* __restrict__ bias_b,
    const float* __restrict__ whh_f, const float* __restrict__ whh_b,
    float* __restrict__ out)
{
    __shared__ float gbuf[2][64 * G4];   // 2 x 20 KB ping-pong (permuted cols)
    int dir  = blockIdx.x >> 6;
    int b    = blockIdx.x & 63;
    int t    = threadIdx.x;
    int wv   = t >> 6;
    int lane = t & 63;

    // ---- gemm-side per-lane constants (waves 1-4) ----
    int mtile = wv - 1;
    int col   = lane & 15;
    int koff  = (lane >> 4) * 8;
    const _Float16* bp = wp + (size_t)(dir * G4 + col) * KPAD + koff;
    float bias_v[5];
    if (wv > 0) {
#pragma unroll
        for (int nf = 0; nf < 5; nf++)
            bias_v[nf] = (dir ? bias_b : bias_f)[nf * 16 + col];
    }

    // ---- recurrence-side per-lane constants (wave 0) ----
    const float* whh = dir ? whh_b : whh_f;
    int j = lane & 31; if (j > 19) j = 19;
    bool low = lane < 32;
    float mm = low ? 1.f : 2.f;
    float aa = low ? 0.f : -1.f;
    int coff = low ? (40 + 2 * j) : (2 * j);
    float w0[HH], w1[HH];
    if (wv == 0) {
        int r0 = low ? (20 + j) : j;
        int r1 = low ? (60 + j) : (40 + j);
#pragma unroll
        for (int k = 0; k < HH; k++) {
            w0[k] = whh[r0 * HH + k];
            w1[k] = whh[r1 * HH + k];
        }
    }

#define COMPUTE_CHUNK(CH, BUF) do {                                             \
    int base_w = dir ? (192 - (CH) * 64) : (CH) * 64;                           \
    int arow = b * 256 + base_w + mtile * 16 + (lane & 15);                     \
    const _Float16* ap = x + (size_t)arow * KPAD + koff;                        \
    f32x4 acc[5];                                                               \
    _Pragma("unroll")                                                           \
    for (int nf = 0; nf < 5; nf++)                                              \
        _Pragma("unroll")                                                       \
        for (int r = 0; r < 4; r++) acc[nf][r] = 0.f;                           \
    for (int k0 = 0; k0 < KPAD; k0 += 32) {                                     \
        f16x8 af = *(const f16x8*)(ap + k0);                                    \
        _Pragma("unroll")                                                       \
        for (int nf = 0; nf < 5; nf++) {                                        \
            f16x8 bf = *(const f16x8*)(bp + (size_t)nf * 16 * KPAD + k0);       \
            acc[nf] = __builtin_amdgcn_mfma_f32_16x16x32_f16(af, bf, acc[nf], 0, 0, 0); \
        }                                                                       \
    }                                                                           \
    int lrow = mtile * 16 + (lane >> 4) * 4;                                    \
    _Pragma("unroll")                                                           \
    for (int nf = 0; nf < 5; nf++) {                                            \
        int g = nf * 16 + col;                                                  \
        int pcol = (g % 40) * 2 + (g / 40);                                     \
        _Pragma("unroll")                                                       \
        for (int r = 0; r < 4; r++)                                             \
            gbuf[BUF][(lrow + r) * G4 + pcol] = acc[nf][r] + bias_v[nf];        \
    }                                                                           \
} while (0)

    if (wv > 0) COMPUTE_CHUNK(0, 0);
    __syncthreads();

    float h = 0.f, c = 0.f;
    int w = dir ? (WW - 1) : 0;
    int stepd = dir ? -1 : 1;

    for (int ch = 0; ch < 4; ++ch) {
        int cb = ch & 1;
        if (wv > 0) {
            if (ch + 1 < 4) COMPUTE_CHUNK(ch + 1, cb ^ 1);
        } else {
            __builtin_amdgcn_s_setprio(1);   // favor the chain wave (T5)
            int base = dir ? (192 - ch * 64) : ch * 64;
            float2 pre = *(const float2*)(&gbuf[cb][(w - base) * G4 + coff]);
            for (int sl = 0; sl < 64; ++sl) {
                int wn = w + stepd;
                float2 nxt = make_float2(0.f, 0.f);
                if (sl < 63)
                    nxt = *(const float2*)(&gbuf[cb][(wn - base) * G4 + coff]);
                float a0a = pre.x, a0b = 0.f, a1a = pre.y, a1b = 0.f;
#pragma unroll
                for (int k = 0; k < 10; k++) {
                    float hk  = __uint_as_float(__builtin_amdgcn_readlane(__float_as_uint(h), k));
                    float hk2 = __uint_as_float(__builtin_amdgcn_readlane(__float_as_uint(h), k + 10));
                    a0a = fmaf(hk,  w0[k],      a0a);
                    a1a = fmaf(hk,  w1[k],      a1a);
                    a0b = fmaf(hk2, w0[k + 10], a0b);
                    a1b = fmaf(hk2, w1[k + 10], a1b);
                }
                float a0 = a0a + a0b, a1 = a1a + a1b;
                float u0 = 1.f / (1.f + __expf(-a0));          // sig(f) | sig(i)
                float uu = 1.f / (1.f + __expf(-mm * a1));
                float u1 = fmaf(uu, mm, aa);                   // sig(o) | tanh(g)
                float p  = u0 * u1;
                float ps = xchg32(p);                          // low gets sig(i)*tanh(g)
                c = fmaf(u0, c, ps);
                float tc = fmaf(2.f, 1.f / (1.f + __expf(-2.f * c)), -1.f);
                h = u1 * tc;
                if (lane < HH)
                    out[((size_t)b * WW + w) * (2 * HH) + dir * HH + lane] = h;
                pre = nxt;
                w = wn;
            }
            __builtin_amdgcn_s_setprio(0);
        }
        __syncthreads();
    }
#undef COMPUTE_CHUNK
}

extern "C" void kernel_launch(void* const* d_in, const int* in_sizes, int n_in,
                              void* d_out, int out_size, void* d_ws, size_t ws_size,
                              hipStream_t stream) {
    const float* hiddens   = (const float*)d_in[0];
    const int*   bert2toks = (const int*)d_in[1];
    const int*   cap_inds  = (const int*)d_in[2];
    const float* cap_table = (const float*)d_in[3];
    const float* w_ih_f    = (const float*)d_in[4];
    const float* w_hh_f    = (const float*)d_in[5];
    const float* b_f       = (const float*)d_in[6];
    const float* w_ih_b    = (const float*)d_in[7];
    const float* w_hh_b    = (const float*)d_in[8];
    const float* b_b       = (const float*)d_in[9];
    float* out = (float*)d_out;

    _Float16* wpad = (_Float16*)((char*)d_ws + WP_OFF);
    int2*     seg  = (int2*)((char*)d_ws + SEG_OFF);
    _Float16* x    = (_Float16*)((char*)d_ws + X_OFF);

    k_mean_prep<<<NMEAN + NPREP, 256, 0, stream>>>(hiddens, bert2toks, cap_inds,
                                                   cap_table, w_ih_f, w_ih_b,
                                                   x, wpad, seg);
    k_lstm<<<128, 320, 0, stream>>>(x, wpad, b_f, b_b, w_hh_f, w_hh_b, out);
}